// Round 5
// baseline (815.304 us; speedup 1.0000x reference)
//
#include <hip/hip_runtime.h>
#include <stdint.h>

#define BETA 0.95f
#define THR  1.0f

__device__ __forceinline__ float bitf(uint32_t w, int sh) {
  return (float)((w >> sh) & 1u);
}

// ---------------- Layer 1 ----------------
// x: [10][8][2][256][320] f32 -> S1: [10][8][128][160] u32 (pooled 32-ch spike mask)
// lane = pre-pool pos; quad of lanes = 2x2 patch; pooled OR via shfl_xor.
__global__ __launch_bounds__(256) void k_l1(const float* __restrict__ x,
                                            const float* __restrict__ w1,
                                            const float* __restrict__ b1,
                                            uint32_t* __restrict__ S1) {
  const int u  = blockIdx.x * 256 + threadIdx.x;  // [0, 655360)
  const int q  = u >> 2;                          // pooled pos [0, 163840)
  const int dx = u & 1, dy = (u >> 1) & 1;
  const int pw = q % 160;
  const int ph = (q / 160) % 128;
  const int b  = q / (160 * 128);
  const int row = 2 * ph + dy;
  const int col = 2 * pw + dx;
  const size_t base = (size_t)row * 320 + col;

  float m[32];
#pragma unroll
  for (int o = 0; o < 32; ++o) m[o] = 0.f;

#pragma unroll 1
  for (int t = 0; t < 10; ++t) {
    const size_t tb = (size_t)(t * 8 + b) * 2 * 81920 + base;
    const float x0 = x[tb];
    const float x1 = x[tb + 81920];
    uint32_t mask = 0u;
#pragma unroll
    for (int o = 0; o < 32; ++o) {
      const float cur = fmaf(w1[o * 2 + 1], x1, fmaf(w1[o * 2], x0, b1[o]));
      float mo = m[o];
      const float rst = (mo > THR) ? THR : 0.f;
      mo = fmaf(BETA, mo, cur) - rst;
      m[o] = mo;
      mask |= (mo > THR) ? (1u << o) : 0u;
    }
    mask |= __shfl_xor(mask, 1, 64);
    mask |= __shfl_xor(mask, 2, 64);
    if ((threadIdx.x & 3) == 0)
      S1[((size_t)(t * 8 + b) * 128 + ph) * 160 + pw] = mask;
  }
}

// ---------------- Layer 2 ----------------
// S1 (u32 masks, 128x160) -> S2: [10][8][64][80][8] u8 (byte g = out-ch 8g..8g+7)
// 256-th block = 4 waves; wave w handles ch-group g = (blockIdx&1)*4+w for the
// same 64-patch chunk (wave-uniform weights; shared S1 reads hit L1).
__global__ __launch_bounds__(256) void k_l2(const uint32_t* __restrict__ S1,
                                            const float* __restrict__ w2,
                                            const float* __restrict__ b2,
                                            uint8_t* __restrict__ S2) {
  const int wave = threadIdx.x >> 6;
  const int lane = threadIdx.x & 63;
  const int g = ((blockIdx.x & 1) << 2) | wave;            // [0,8)
  const int patch = (blockIdx.x >> 1) * 64 + lane;         // pooled pos [0, 40960)
  const int pw = patch % 80;
  const int py = (patch / 80) % 64;
  const int b  = patch / (80 * 64);
  const size_t base0 = ((size_t)b * 128 + 2 * py) * 160 + 2 * pw;

  float m[4][8];
#pragma unroll
  for (int p = 0; p < 4; ++p)
#pragma unroll
    for (int o = 0; o < 8; ++o) m[p][o] = 0.f;

#pragma unroll 1
  for (int t = 0; t < 10; ++t) {
    const size_t off = (size_t)t * 8 * 128 * 160 + base0;
    const uint2 va = *(const uint2*)(S1 + off);
    const uint2 vb = *(const uint2*)(S1 + off + 160);
    const uint32_t msk[4] = {va.x, va.y, vb.x, vb.y};

    float cur[4][8];
#pragma unroll
    for (int p = 0; p < 4; ++p)
#pragma unroll
      for (int oo = 0; oo < 8; ++oo) cur[p][oo] = b2[g * 8 + oo];
#pragma unroll
    for (int cq = 0; cq < 8; ++cq) {
      float sp[4][4];
#pragma unroll
      for (int p = 0; p < 4; ++p)
#pragma unroll
        for (int j = 0; j < 4; ++j) sp[p][j] = bitf(msk[p], 4 * cq + j);
#pragma unroll
      for (int oo = 0; oo < 8; ++oo) {
        const float4 wv = *(const float4*)(w2 + ((g * 8 + oo) * 32 + 4 * cq));
#pragma unroll
        for (int p = 0; p < 4; ++p) {
          float a = cur[p][oo];
          a = fmaf(wv.x, sp[p][0], a);
          a = fmaf(wv.y, sp[p][1], a);
          a = fmaf(wv.z, sp[p][2], a);
          a = fmaf(wv.w, sp[p][3], a);
          cur[p][oo] = a;
        }
      }
    }
    uint32_t pooled = 0u;
#pragma unroll
    for (int oo = 0; oo < 8; ++oo)
#pragma unroll
      for (int p = 0; p < 4; ++p) {
        float mo = m[p][oo];
        const float rst = (mo > THR) ? THR : 0.f;
        mo = fmaf(BETA, mo, cur[p][oo]) - rst;
        m[p][oo] = mo;
        pooled |= (mo > THR) ? (1u << oo) : 0u;
      }
    S2[((size_t)((t * 8 + b) * 64 + py) * 80 + pw) * 8 + g] = (uint8_t)pooled;
  }
}

// ---------------- Layer 3 ----------------
// S2 (8B/pos, 64x80) -> S3: [10][8][32][40][8] u8. lane = pre-pool pos, quad pooling;
// wave w handles g = (blockIdx&1)*4+w (8 out-ch each).
__global__ __launch_bounds__(256) void k_l3(const uint8_t* __restrict__ S2,
                                            const float* __restrict__ w3,
                                            const float* __restrict__ b3,
                                            uint8_t* __restrict__ S3) {
  const int wave = threadIdx.x >> 6;
  const int lane = threadIdx.x & 63;
  const int g = ((blockIdx.x & 1) << 2) | wave;            // [0,8)
  const int posu = (blockIdx.x >> 1) * 64 + lane;          // pre-pool pos [0, 40960)
  const int qq = posu >> 2;
  const int dx = posu & 1, dy = (posu >> 1) & 1;
  const int px = qq % 40;
  const int py = (qq / 40) % 32;
  const int b  = qq / 1280;
  const int row = 2 * py + dy;
  const int col = 2 * px + dx;
  const size_t base = ((size_t)(b * 64 + row) * 80 + col) * 8;

  float m[8];
#pragma unroll
  for (int o = 0; o < 8; ++o) m[o] = 0.f;

#pragma unroll 1
  for (int t = 0; t < 10; ++t) {
    const uint2 v = *(const uint2*)(S2 + (size_t)t * 8 * 64 * 80 * 8 + base);
    const uint32_t lo = v.x, hi = v.y;

    float cur[8];
#pragma unroll
    for (int oo = 0; oo < 8; ++oo) cur[oo] = b3[g * 8 + oo];
#pragma unroll
    for (int cq = 0; cq < 16; ++cq) {
      float sp[4];
#pragma unroll
      for (int j = 0; j < 4; ++j)
        sp[j] = bitf((cq < 8) ? lo : hi, (4 * cq + j) & 31);
#pragma unroll
      for (int oo = 0; oo < 8; ++oo) {
        const float4 wv = *(const float4*)(w3 + ((g * 8 + oo) * 64 + 4 * cq));
        float a = cur[oo];
        a = fmaf(wv.x, sp[0], a);
        a = fmaf(wv.y, sp[1], a);
        a = fmaf(wv.z, sp[2], a);
        a = fmaf(wv.w, sp[3], a);
        cur[oo] = a;
      }
    }
    uint32_t pooled = 0u;
#pragma unroll
    for (int oo = 0; oo < 8; ++oo) {
      float mo = m[oo];
      const float rst = (mo > THR) ? THR : 0.f;
      mo = fmaf(BETA, mo, cur[oo]) - rst;
      m[oo] = mo;
      pooled |= (mo > THR) ? (1u << oo) : 0u;
    }
    pooled |= __shfl_xor(pooled, 1, 64);
    pooled |= __shfl_xor(pooled, 2, 64);
    if ((lane & 3) == 0)
      S3[((size_t)((t * 8 + b) * 32 + py) * 40 + px) * 8 + g] = (uint8_t)pooled;
  }
}

// ---------------- Layer 4 ----------------
// S3 (8B/pos, 32x40) -> S4: [10][8][16][20][32] u8 (byte g = nibble, ch 4g..4g+3)
// wave w handles g = (blockIdx&7)*4+w (4 out-ch each).
__global__ __launch_bounds__(256) void k_l4(const uint8_t* __restrict__ S3,
                                            const float* __restrict__ w4,
                                            const float* __restrict__ b4,
                                            uint8_t* __restrict__ S4) {
  const int wave = threadIdx.x >> 6;
  const int lane = threadIdx.x & 63;
  const int g = ((blockIdx.x & 7) << 2) | wave;            // [0,32)
  const int posu = (blockIdx.x >> 3) * 64 + lane;          // pre-pool pos [0, 10240)
  const int qq = posu >> 2;
  const int dx = posu & 1, dy = (posu >> 1) & 1;
  const int px = qq % 20;
  const int py = (qq / 20) % 16;
  const int b  = qq / 320;
  const int row = 2 * py + dy;
  const int col = 2 * px + dx;
  const size_t base = ((size_t)(b * 32 + row) * 40 + col) * 8;

  float m[4];
#pragma unroll
  for (int o = 0; o < 4; ++o) m[o] = 0.f;

#pragma unroll 1
  for (int t = 0; t < 10; ++t) {
    const uint2 v = *(const uint2*)(S3 + (size_t)t * 8 * 32 * 40 * 8 + base);
    const uint32_t lo = v.x, hi = v.y;

    float cur[4];
#pragma unroll
    for (int oo = 0; oo < 4; ++oo) cur[oo] = b4[g * 4 + oo];
#pragma unroll
    for (int cq = 0; cq < 16; ++cq) {
      float sp[4];
#pragma unroll
      for (int j = 0; j < 4; ++j)
        sp[j] = bitf((cq < 8) ? lo : hi, (4 * cq + j) & 31);
#pragma unroll
      for (int oo = 0; oo < 4; ++oo) {
        const float4 wv = *(const float4*)(w4 + ((g * 4 + oo) * 64 + 4 * cq));
        float a = cur[oo];
        a = fmaf(wv.x, sp[0], a);
        a = fmaf(wv.y, sp[1], a);
        a = fmaf(wv.z, sp[2], a);
        a = fmaf(wv.w, sp[3], a);
        cur[oo] = a;
      }
    }
    uint32_t pooled = 0u;
#pragma unroll
    for (int oo = 0; oo < 4; ++oo) {
      float mo = m[oo];
      const float rst = (mo > THR) ? THR : 0.f;
      mo = fmaf(BETA, mo, cur[oo]) - rst;
      m[oo] = mo;
      pooled |= (mo > THR) ? (1u << oo) : 0u;
    }
    pooled |= __shfl_xor(pooled, 1, 64);
    pooled |= __shfl_xor(pooled, 2, 64);
    if ((lane & 3) == 0)
      S4[((size_t)((t * 8 + b) * 16 + py) * 20 + px) * 32 + g] = (uint8_t)pooled;
  }
}

// ---------------- Layer 5 ----------------
// S4 (32B/pos nibbles, 16x20) -> s: [8][10240] f32 spike-count.
// wave w handles g = (blockIdx&15)*4+w (2 out-ch each).
__global__ __launch_bounds__(256) void k_l5(const uint8_t* __restrict__ S4,
                                            const float* __restrict__ w5,
                                            const float* __restrict__ b5,
                                            float* __restrict__ s) {
  const int wave = threadIdx.x >> 6;
  const int lane = threadIdx.x & 63;
  const int g = ((blockIdx.x & 15) << 2) | wave;           // [0,64)
  const int posu = (blockIdx.x >> 4) * 64 + lane;          // pre-pool pos [0, 2560)
  const int qq = posu >> 2;
  const int dx = posu & 1, dy = (posu >> 1) & 1;
  const int px = qq % 10;
  const int py = (qq / 10) % 8;
  const int b  = qq / 80;
  const int row = 2 * py + dy;
  const int col = 2 * px + dx;
  const size_t base = ((size_t)(b * 16 + row) * 20 + col) * 32;

  float m[2] = {0.f, 0.f}, scnt[2] = {0.f, 0.f};

#pragma unroll 1
  for (int t = 0; t < 10; ++t) {
    const size_t off = (size_t)t * 8 * 16 * 20 * 32 + base;
    const uint4 v0 = *(const uint4*)(S4 + off);
    const uint4 v1 = *(const uint4*)(S4 + off + 16);
    const uint32_t wrd[8] = {v0.x, v0.y, v0.z, v0.w, v1.x, v1.y, v1.z, v1.w};

    float cur[2];
#pragma unroll
    for (int oo = 0; oo < 2; ++oo) cur[oo] = b5[g * 2 + oo];
#pragma unroll
    for (int cq = 0; cq < 32; ++cq) {   // byte cq holds in-ch 4cq..4cq+3 (low nibble)
      float sp[4];
#pragma unroll
      for (int j = 0; j < 4; ++j)
        sp[j] = bitf(wrd[cq >> 2], (cq & 3) * 8 + j);
#pragma unroll
      for (int oo = 0; oo < 2; ++oo) {
        const float4 wv = *(const float4*)(w5 + ((g * 2 + oo) * 128 + 4 * cq));
        float a = cur[oo];
        a = fmaf(wv.x, sp[0], a);
        a = fmaf(wv.y, sp[1], a);
        a = fmaf(wv.z, sp[2], a);
        a = fmaf(wv.w, sp[3], a);
        cur[oo] = a;
      }
    }
    uint32_t pooled = 0u;
#pragma unroll
    for (int oo = 0; oo < 2; ++oo) {
      float mo = m[oo];
      const float rst = (mo > THR) ? THR : 0.f;
      mo = fmaf(BETA, mo, cur[oo]) - rst;
      m[oo] = mo;
      pooled |= (mo > THR) ? (1u << oo) : 0u;
    }
    pooled |= __shfl_xor(pooled, 1, 64);
    pooled |= __shfl_xor(pooled, 2, 64);
#pragma unroll
    for (int oo = 0; oo < 2; ++oo) scnt[oo] += bitf(pooled, oo);
  }
  if ((lane & 3) == 0) {
#pragma unroll
    for (int oo = 0; oo < 2; ++oo)
      s[b * 10240 + (g * 2 + oo) * 80 + py * 10 + px] = scnt[oo];
  }
}

// ---------------- FC1 (partial GEMV, K split 8 ways, float4 loads) ----------------
// 256-th block = 4 wave-tasks; wtid = (o8 in [0,512), kq in [0,8)); pt: [8][8][4096]
__global__ __launch_bounds__(256) void k_fc1(const float* __restrict__ s,
                                             const float* __restrict__ W,
                                             float* __restrict__ pt) {
  const int wave = threadIdx.x >> 6;
  const int lane = threadIdx.x & 63;
  const int wtid = blockIdx.x * 4 + wave;
  const int o8 = wtid & 511;
  const int kq = wtid >> 9;

  float acc[8][8];
#pragma unroll
  for (int os = 0; os < 8; ++os)
#pragma unroll
    for (int bb = 0; bb < 8; ++bb) acc[os][bb] = 0.f;

#pragma unroll 1
  for (int it = 0; it < 5; ++it) {
    const int k = kq * 1280 + it * 256 + lane * 4;
    float4 sv[8];
#pragma unroll
    for (int bb = 0; bb < 8; ++bb) sv[bb] = *(const float4*)(s + bb * 10240 + k);
#pragma unroll
    for (int os = 0; os < 8; ++os) {
      const float4 wv = *(const float4*)(W + (size_t)(o8 * 8 + os) * 10240 + k);
#pragma unroll
      for (int bb = 0; bb < 8; ++bb) {
        float a = acc[os][bb];
        a = fmaf(wv.x, sv[bb].x, a);
        a = fmaf(wv.y, sv[bb].y, a);
        a = fmaf(wv.z, sv[bb].z, a);
        a = fmaf(wv.w, sv[bb].w, a);
        acc[os][bb] = a;
      }
    }
  }
#pragma unroll
  for (int os = 0; os < 8; ++os)
#pragma unroll
    for (int bb = 0; bb < 8; ++bb) {
      float v = acc[os][bb];
#pragma unroll
      for (int mq = 1; mq < 64; mq <<= 1) v += __shfl_xor(v, mq, 64);
      acc[os][bb] = v;
    }
  float out = 0.f;
#pragma unroll
  for (int os = 0; os < 8; ++os)
#pragma unroll
    for (int bb = 0; bb < 8; ++bb)
      out = (lane == os * 8 + bb) ? acc[os][bb] : out;
  const int os = lane >> 3;
  const int bb = lane & 7;
  pt[((kq * 8 + bb) * 4096) + o8 * 8 + os] = out;
}

// ---------------- FC2 partial (reduce K-partials + spike + partial GEMV) -------
// grid: b(8) x j(4) x oc(4); each block reduces 1024 outputs of fc1.
__global__ __launch_bounds__(64) void k_fc2p(const float* __restrict__ pt,
                                             const float* __restrict__ fc1_b,
                                             const float* __restrict__ fc2_w,
                                             float* __restrict__ pt2) {
  const int lane = threadIdx.x;
  const int b  = blockIdx.x >> 4;
  const int j  = (blockIdx.x >> 2) & 3;
  const int oc = blockIdx.x & 3;
  float acc = 0.f;
#pragma unroll 2
  for (int it = 0; it < 16; ++it) {
    const int o = oc * 1024 + it * 64 + lane;
    float m1 = fc1_b[o];
#pragma unroll
    for (int kq = 0; kq < 8; ++kq) m1 += pt[(kq * 8 + b) * 4096 + o];
    acc += (m1 > THR) ? fc2_w[j * 4096 + o] : 0.f;
  }
#pragma unroll
  for (int mq = 1; mq < 64; mq <<= 1) acc += __shfl_xor(acc, mq, 64);
  if (lane == 0) pt2[blockIdx.x] = acc;
}

// ---------------- FC3 (final tiny reduce) ----------------
__global__ __launch_bounds__(64) void k_fc3(const float* __restrict__ pt2,
                                            const float* __restrict__ fc2_b,
                                            float* __restrict__ out) {
  const int lane = threadIdx.x;
  if (lane < 32) {
    const int b = lane >> 2;
    const int j = lane & 3;
    float acc = fc2_b[j];
#pragma unroll
    for (int oc = 0; oc < 4; ++oc) acc += pt2[b * 16 + j * 4 + oc];
    out[b * 4 + j] = acc;
  }
}

extern "C" void kernel_launch(void* const* d_in, const int* in_sizes, int n_in,
                              void* d_out, int out_size, void* d_ws, size_t ws_size,
                              hipStream_t stream) {
  const float* x     = (const float*)d_in[0];
  const float* w1    = (const float*)d_in[1];
  const float* b1    = (const float*)d_in[2];
  const float* w2    = (const float*)d_in[3];
  const float* b2    = (const float*)d_in[4];
  const float* w3    = (const float*)d_in[5];
  const float* b3    = (const float*)d_in[6];
  const float* w4    = (const float*)d_in[7];
  const float* b4    = (const float*)d_in[8];
  const float* w5    = (const float*)d_in[9];
  const float* b5    = (const float*)d_in[10];
  const float* fc1w  = (const float*)d_in[11];
  const float* fc1b  = (const float*)d_in[12];
  const float* fc2w  = (const float*)d_in[13];
  const float* fc2b  = (const float*)d_in[14];

  uint8_t* ws = (uint8_t*)d_ws;
  uint32_t* S1  = (uint32_t*)(ws + 0);          //  6,553,600 B [10][8][128][160] u32
  uint8_t*  S2  = ws + 6553600;                 //  3,276,800 B [10][8][64][80][8] u8
  uint8_t*  S3  = ws + 9830400;                 //    819,200 B [10][8][32][40][8] u8
  uint8_t*  S4  = ws + 10649600;                //    819,200 B [10][8][16][20][32] u8
  float*    sb  = (float*)(ws + 11468800);      //    327,680 B [8][10240] f32
  float*    pt  = (float*)(ws + 11796480);      //  1,048,576 B [8][8][4096] f32
  float*    pt2 = (float*)(ws + 12845056);      //        512 B [128] f32

  k_l1 <<<2560, 256, 0, stream>>>(x, w1, b1, S1);
  k_l2 <<<1280, 256, 0, stream>>>(S1, w2, b2, S2);
  k_l3 <<<1280, 256, 0, stream>>>(S2, w3, b3, S3);
  k_l4 <<<1280, 256, 0, stream>>>(S3, w4, b4, S4);
  k_l5 <<< 640, 256, 0, stream>>>(S4, w5, b5, sb);
  k_fc1<<<1024, 256, 0, stream>>>(sb, fc1w, pt);
  k_fc2p<<<128, 64, 0, stream>>>(pt, fc1b, fc2w, pt2);
  k_fc3<<<   1, 64, 0, stream>>>(pt2, fc2b, (float*)d_out);
}

// Round 7
// 686.131 us; speedup vs baseline: 1.1883x; 1.1883x over previous
//
#include <hip/hip_runtime.h>
#include <stdint.h>

#define BETA 0.95f
#define THR  1.0f

__device__ __forceinline__ float bitf(uint32_t w, int sh) {
  return (float)((w >> sh) & 1u);
}

// ---------------- Layer 1 ----------------
// x: [10][8][2][256][320] f32 -> S1: [10][8][128][160] u32 (pooled 32-ch spike mask)
// lane = pre-pool pos; quad of lanes = 2x2 patch; pooled OR via shfl_xor.
__global__ __launch_bounds__(256) void k_l1(const float* __restrict__ x,
                                            const float* __restrict__ w1,
                                            const float* __restrict__ b1,
                                            uint32_t* __restrict__ S1) {
  const int u  = blockIdx.x * 256 + threadIdx.x;  // [0, 655360)
  const int q  = u >> 2;                          // pooled pos [0, 163840)
  const int dx = u & 1, dy = (u >> 1) & 1;
  const int pw = q % 160;
  const int ph = (q / 160) % 128;
  const int b  = q / (160 * 128);
  const int row = 2 * ph + dy;
  const int col = 2 * pw + dx;
  const size_t base = (size_t)row * 320 + col;

  float m[32];
#pragma unroll
  for (int o = 0; o < 32; ++o) m[o] = 0.f;

#pragma unroll 1
  for (int t = 0; t < 10; ++t) {
    const size_t tb = (size_t)(t * 8 + b) * 2 * 81920 + base;
    const float x0 = x[tb];
    const float x1 = x[tb + 81920];
    uint32_t mask = 0u;
#pragma unroll
    for (int o = 0; o < 32; ++o) {
      const float cur = fmaf(w1[o * 2 + 1], x1, fmaf(w1[o * 2], x0, b1[o]));
      float mo = m[o];
      const float rst = (mo > THR) ? THR : 0.f;
      mo = fmaf(BETA, mo, cur) - rst;
      m[o] = mo;
      mask |= (mo > THR) ? (1u << o) : 0u;
    }
    mask |= __shfl_xor(mask, 1, 64);
    mask |= __shfl_xor(mask, 2, 64);
    if ((threadIdx.x & 3) == 0)
      S1[((size_t)(t * 8 + b) * 128 + ph) * 160 + pw] = mask;
  }
}

// ---------------- Layer 2 ----------------
// S1 (u32 masks, 128x160) -> S2: [10][8][64][80][8] u8 (byte g = out-ch 8g..8g+7)
// g = blockIdx-only (scalar s_load weights); 256-th block = 4 waves over 256 patches.
__global__ __launch_bounds__(256) void k_l2(const uint32_t* __restrict__ S1,
                                            const float* __restrict__ w2,
                                            const float* __restrict__ b2,
                                            uint8_t* __restrict__ S2) {
  const int g = blockIdx.x & 7;                              // [0,8)
  const int patch = (blockIdx.x >> 3) * 256 + threadIdx.x;   // pooled pos [0, 40960)
  const int pw = patch % 80;
  const int py = (patch / 80) % 64;
  const int b  = patch / (80 * 64);
  const size_t base0 = ((size_t)b * 128 + 2 * py) * 160 + 2 * pw;

  float m[4][8];
#pragma unroll
  for (int p = 0; p < 4; ++p)
#pragma unroll
    for (int o = 0; o < 8; ++o) m[p][o] = 0.f;

#pragma unroll 1
  for (int t = 0; t < 10; ++t) {
    const size_t off = (size_t)t * 8 * 128 * 160 + base0;
    const uint2 va = *(const uint2*)(S1 + off);
    const uint2 vb = *(const uint2*)(S1 + off + 160);
    const uint32_t msk[4] = {va.x, va.y, vb.x, vb.y};

    float cur[4][8];
#pragma unroll
    for (int p = 0; p < 4; ++p)
#pragma unroll
      for (int oo = 0; oo < 8; ++oo) cur[p][oo] = b2[g * 8 + oo];
#pragma unroll
    for (int cq = 0; cq < 8; ++cq) {
      float sp[4][4];
#pragma unroll
      for (int p = 0; p < 4; ++p)
#pragma unroll
        for (int j = 0; j < 4; ++j) sp[p][j] = bitf(msk[p], 4 * cq + j);
#pragma unroll
      for (int oo = 0; oo < 8; ++oo) {
        const float4 wv = *(const float4*)(w2 + ((g * 8 + oo) * 32 + 4 * cq));
#pragma unroll
        for (int p = 0; p < 4; ++p) {
          float a = cur[p][oo];
          a = fmaf(wv.x, sp[p][0], a);
          a = fmaf(wv.y, sp[p][1], a);
          a = fmaf(wv.z, sp[p][2], a);
          a = fmaf(wv.w, sp[p][3], a);
          cur[p][oo] = a;
        }
      }
    }
    uint32_t pooled = 0u;
#pragma unroll
    for (int oo = 0; oo < 8; ++oo)
#pragma unroll
      for (int p = 0; p < 4; ++p) {
        float mo = m[p][oo];
        const float rst = (mo > THR) ? THR : 0.f;
        mo = fmaf(BETA, mo, cur[p][oo]) - rst;
        m[p][oo] = mo;
        pooled |= (mo > THR) ? (1u << oo) : 0u;
      }
    S2[((size_t)((t * 8 + b) * 64 + py) * 80 + pw) * 8 + g] = (uint8_t)pooled;
  }
}

// ---------------- Layer 3 ----------------
// S2 (8B/pos, 64x80) -> S3: [10][8][32][40][8] u8. lane = pre-pool pos, quad pooling;
// g = blockIdx-only (8 out-ch per thread).
__global__ __launch_bounds__(256) void k_l3(const uint8_t* __restrict__ S2,
                                            const float* __restrict__ w3,
                                            const float* __restrict__ b3,
                                            uint8_t* __restrict__ S3) {
  const int g = blockIdx.x & 7;                              // [0,8)
  const int posu = (blockIdx.x >> 3) * 256 + threadIdx.x;    // pre-pool pos [0, 40960)
  const int qq = posu >> 2;
  const int dx = posu & 1, dy = (posu >> 1) & 1;
  const int px = qq % 40;
  const int py = (qq / 40) % 32;
  const int b  = qq / 1280;
  const int row = 2 * py + dy;
  const int col = 2 * px + dx;
  const size_t base = ((size_t)(b * 64 + row) * 80 + col) * 8;

  float m[8];
#pragma unroll
  for (int o = 0; o < 8; ++o) m[o] = 0.f;

#pragma unroll 1
  for (int t = 0; t < 10; ++t) {
    const uint2 v = *(const uint2*)(S2 + (size_t)t * 8 * 64 * 80 * 8 + base);
    const uint32_t lo = v.x, hi = v.y;

    float cur[8];
#pragma unroll
    for (int oo = 0; oo < 8; ++oo) cur[oo] = b3[g * 8 + oo];
#pragma unroll
    for (int cq = 0; cq < 16; ++cq) {
      float sp[4];
#pragma unroll
      for (int j = 0; j < 4; ++j)
        sp[j] = bitf((cq < 8) ? lo : hi, (4 * cq + j) & 31);
#pragma unroll
      for (int oo = 0; oo < 8; ++oo) {
        const float4 wv = *(const float4*)(w3 + ((g * 8 + oo) * 64 + 4 * cq));
        float a = cur[oo];
        a = fmaf(wv.x, sp[0], a);
        a = fmaf(wv.y, sp[1], a);
        a = fmaf(wv.z, sp[2], a);
        a = fmaf(wv.w, sp[3], a);
        cur[oo] = a;
      }
    }
    uint32_t pooled = 0u;
#pragma unroll
    for (int oo = 0; oo < 8; ++oo) {
      float mo = m[oo];
      const float rst = (mo > THR) ? THR : 0.f;
      mo = fmaf(BETA, mo, cur[oo]) - rst;
      m[oo] = mo;
      pooled |= (mo > THR) ? (1u << oo) : 0u;
    }
    pooled |= __shfl_xor(pooled, 1, 64);
    pooled |= __shfl_xor(pooled, 2, 64);
    if ((threadIdx.x & 3) == 0)
      S3[((size_t)((t * 8 + b) * 32 + py) * 40 + px) * 8 + g] = (uint8_t)pooled;
  }
}

// ---------------- Layer 4 ----------------
// S3 (8B/pos, 32x40) -> S4: [10][8][16][20][32] u8 (byte g = nibble, ch 4g..4g+3)
// g = blockIdx-only (4 out-ch per thread).
__global__ __launch_bounds__(256) void k_l4(const uint8_t* __restrict__ S3,
                                            const float* __restrict__ w4,
                                            const float* __restrict__ b4,
                                            uint8_t* __restrict__ S4) {
  const int g = blockIdx.x & 31;                             // [0,32)
  const int posu = (blockIdx.x >> 5) * 256 + threadIdx.x;    // pre-pool pos [0, 10240)
  const int qq = posu >> 2;
  const int dx = posu & 1, dy = (posu >> 1) & 1;
  const int px = qq % 20;
  const int py = (qq / 20) % 16;
  const int b  = qq / 320;
  const int row = 2 * py + dy;
  const int col = 2 * px + dx;
  const size_t base = ((size_t)(b * 32 + row) * 40 + col) * 8;

  float m[4];
#pragma unroll
  for (int o = 0; o < 4; ++o) m[o] = 0.f;

#pragma unroll 1
  for (int t = 0; t < 10; ++t) {
    const uint2 v = *(const uint2*)(S3 + (size_t)t * 8 * 32 * 40 * 8 + base);
    const uint32_t lo = v.x, hi = v.y;

    float cur[4];
#pragma unroll
    for (int oo = 0; oo < 4; ++oo) cur[oo] = b4[g * 4 + oo];
#pragma unroll
    for (int cq = 0; cq < 16; ++cq) {
      float sp[4];
#pragma unroll
      for (int j = 0; j < 4; ++j)
        sp[j] = bitf((cq < 8) ? lo : hi, (4 * cq + j) & 31);
#pragma unroll
      for (int oo = 0; oo < 4; ++oo) {
        const float4 wv = *(const float4*)(w4 + ((g * 4 + oo) * 64 + 4 * cq));
        float a = cur[oo];
        a = fmaf(wv.x, sp[0], a);
        a = fmaf(wv.y, sp[1], a);
        a = fmaf(wv.z, sp[2], a);
        a = fmaf(wv.w, sp[3], a);
        cur[oo] = a;
      }
    }
    uint32_t pooled = 0u;
#pragma unroll
    for (int oo = 0; oo < 4; ++oo) {
      float mo = m[oo];
      const float rst = (mo > THR) ? THR : 0.f;
      mo = fmaf(BETA, mo, cur[oo]) - rst;
      m[oo] = mo;
      pooled |= (mo > THR) ? (1u << oo) : 0u;
    }
    pooled |= __shfl_xor(pooled, 1, 64);
    pooled |= __shfl_xor(pooled, 2, 64);
    if ((threadIdx.x & 3) == 0)
      S4[((size_t)((t * 8 + b) * 16 + py) * 20 + px) * 32 + g] = (uint8_t)pooled;
  }
}

// ---------------- Layer 5 ----------------
// S4 (32B/pos nibbles, 16x20) -> s: [8][10240] f32 spike-count.
// g = blockIdx-only (2 out-ch per thread).
__global__ __launch_bounds__(256) void k_l5(const uint8_t* __restrict__ S4,
                                            const float* __restrict__ w5,
                                            const float* __restrict__ b5,
                                            float* __restrict__ s) {
  const int g = blockIdx.x & 63;                             // [0,64)
  const int posu = (blockIdx.x >> 6) * 256 + threadIdx.x;    // pre-pool pos [0, 2560)
  const int qq = posu >> 2;
  const int dx = posu & 1, dy = (posu >> 1) & 1;
  const int px = qq % 10;
  const int py = (qq / 10) % 8;
  const int b  = qq / 80;
  const int row = 2 * py + dy;
  const int col = 2 * px + dx;
  const size_t base = ((size_t)(b * 16 + row) * 20 + col) * 32;

  float m[2] = {0.f, 0.f}, scnt[2] = {0.f, 0.f};

#pragma unroll 1
  for (int t = 0; t < 10; ++t) {
    const size_t off = (size_t)t * 8 * 16 * 20 * 32 + base;
    const uint4 v0 = *(const uint4*)(S4 + off);
    const uint4 v1 = *(const uint4*)(S4 + off + 16);
    const uint32_t wrd[8] = {v0.x, v0.y, v0.z, v0.w, v1.x, v1.y, v1.z, v1.w};

    float cur[2];
#pragma unroll
    for (int oo = 0; oo < 2; ++oo) cur[oo] = b5[g * 2 + oo];
#pragma unroll
    for (int cq = 0; cq < 32; ++cq) {   // byte cq holds in-ch 4cq..4cq+3 (low nibble)
      float sp[4];
#pragma unroll
      for (int j = 0; j < 4; ++j)
        sp[j] = bitf(wrd[cq >> 2], (cq & 3) * 8 + j);
#pragma unroll
      for (int oo = 0; oo < 2; ++oo) {
        const float4 wv = *(const float4*)(w5 + ((g * 2 + oo) * 128 + 4 * cq));
        float a = cur[oo];
        a = fmaf(wv.x, sp[0], a);
        a = fmaf(wv.y, sp[1], a);
        a = fmaf(wv.z, sp[2], a);
        a = fmaf(wv.w, sp[3], a);
        cur[oo] = a;
      }
    }
    uint32_t pooled = 0u;
#pragma unroll
    for (int oo = 0; oo < 2; ++oo) {
      float mo = m[oo];
      const float rst = (mo > THR) ? THR : 0.f;
      mo = fmaf(BETA, mo, cur[oo]) - rst;
      m[oo] = mo;
      pooled |= (mo > THR) ? (1u << oo) : 0u;
    }
    pooled |= __shfl_xor(pooled, 1, 64);
    pooled |= __shfl_xor(pooled, 2, 64);
#pragma unroll
    for (int oo = 0; oo < 2; ++oo) scnt[oo] += bitf(pooled, oo);
  }
  if ((threadIdx.x & 3) == 0) {
#pragma unroll
    for (int oo = 0; oo < 2; ++oo)
      s[b * 10240 + (g * 2 + oo) * 80 + py * 10 + px] = scnt[oo];
  }
}

// ---------------- FC1 (partial GEMV, K split 8 ways, float4 loads) ----------------
// 256-th block = 4 wave-tasks; wtid = (o8 in [0,512), kq in [0,8)); pt: [8][8][4096]
__global__ __launch_bounds__(256) void k_fc1(const float* __restrict__ s,
                                             const float* __restrict__ W,
                                             float* __restrict__ pt) {
  const int wave = threadIdx.x >> 6;
  const int lane = threadIdx.x & 63;
  const int wtid = blockIdx.x * 4 + wave;
  const int o8 = wtid & 511;
  const int kq = wtid >> 9;

  float acc[8][8];
#pragma unroll
  for (int os = 0; os < 8; ++os)
#pragma unroll
    for (int bb = 0; bb < 8; ++bb) acc[os][bb] = 0.f;

#pragma unroll 1
  for (int it = 0; it < 5; ++it) {
    const int k = kq * 1280 + it * 256 + lane * 4;
    float4 sv[8];
#pragma unroll
    for (int bb = 0; bb < 8; ++bb) sv[bb] = *(const float4*)(s + bb * 10240 + k);
#pragma unroll
    for (int os = 0; os < 8; ++os) {
      const float4 wv = *(const float4*)(W + (size_t)(o8 * 8 + os) * 10240 + k);
#pragma unroll
      for (int bb = 0; bb < 8; ++bb) {
        float a = acc[os][bb];
        a = fmaf(wv.x, sv[bb].x, a);
        a = fmaf(wv.y, sv[bb].y, a);
        a = fmaf(wv.z, sv[bb].z, a);
        a = fmaf(wv.w, sv[bb].w, a);
        acc[os][bb] = a;
      }
    }
  }
#pragma unroll
  for (int os = 0; os < 8; ++os)
#pragma unroll
    for (int bb = 0; bb < 8; ++bb) {
      float v = acc[os][bb];
#pragma unroll
      for (int mq = 1; mq < 64; mq <<= 1) v += __shfl_xor(v, mq, 64);
      acc[os][bb] = v;
    }
  float out = 0.f;
#pragma unroll
  for (int os = 0; os < 8; ++os)
#pragma unroll
    for (int bb = 0; bb < 8; ++bb)
      out = (lane == os * 8 + bb) ? acc[os][bb] : out;
  const int os = lane >> 3;
  const int bb = lane & 7;
  pt[((kq * 8 + bb) * 4096) + o8 * 8 + os] = out;
}

// ---------------- FC2 partial (reduce K-partials + spike + partial GEMV) -------
// grid: b(8) x j(4) x oc(4); each block reduces 1024 outputs of fc1.
__global__ __launch_bounds__(64) void k_fc2p(const float* __restrict__ pt,
                                             const float* __restrict__ fc1_b,
                                             const float* __restrict__ fc2_w,
                                             float* __restrict__ pt2) {
  const int lane = threadIdx.x;
  const int b  = blockIdx.x >> 4;
  const int j  = (blockIdx.x >> 2) & 3;
  const int oc = blockIdx.x & 3;
  float acc = 0.f;
#pragma unroll 2
  for (int it = 0; it < 16; ++it) {
    const int o = oc * 1024 + it * 64 + lane;
    float m1 = fc1_b[o];
#pragma unroll
    for (int kq = 0; kq < 8; ++kq) m1 += pt[(kq * 8 + b) * 4096 + o];
    acc += (m1 > THR) ? fc2_w[j * 4096 + o] : 0.f;
  }
#pragma unroll
  for (int mq = 1; mq < 64; mq <<= 1) acc += __shfl_xor(acc, mq, 64);
  if (lane == 0) pt2[blockIdx.x] = acc;
}

// ---------------- FC3 (final tiny reduce) ----------------
__global__ __launch_bounds__(64) void k_fc3(const float* __restrict__ pt2,
                                            const float* __restrict__ fc2_b,
                                            float* __restrict__ out) {
  const int lane = threadIdx.x;
  if (lane < 32) {
    const int b = lane >> 2;
    const int j = lane & 3;
    float acc = fc2_b[j];
#pragma unroll
    for (int oc = 0; oc < 4; ++oc) acc += pt2[b * 16 + j * 4 + oc];
    out[b * 4 + j] = acc;
  }
}

extern "C" void kernel_launch(void* const* d_in, const int* in_sizes, int n_in,
                              void* d_out, int out_size, void* d_ws, size_t ws_size,
                              hipStream_t stream) {
  const float* x     = (const float*)d_in[0];
  const float* w1    = (const float*)d_in[1];
  const float* b1    = (const float*)d_in[2];
  const float* w2    = (const float*)d_in[3];
  const float* b2    = (const float*)d_in[4];
  const float* w3    = (const float*)d_in[5];
  const float* b3    = (const float*)d_in[6];
  const float* w4    = (const float*)d_in[7];
  const float* b4    = (const float*)d_in[8];
  const float* w5    = (const float*)d_in[9];
  const float* b5    = (const float*)d_in[10];
  const float* fc1w  = (const float*)d_in[11];
  const float* fc1b  = (const float*)d_in[12];
  const float* fc2w  = (const float*)d_in[13];
  const float* fc2b  = (const float*)d_in[14];

  uint8_t* ws = (uint8_t*)d_ws;
  uint32_t* S1  = (uint32_t*)(ws + 0);          //  6,553,600 B [10][8][128][160] u32
  uint8_t*  S2  = ws + 6553600;                 //  3,276,800 B [10][8][64][80][8] u8
  uint8_t*  S3  = ws + 9830400;                 //    819,200 B [10][8][32][40][8] u8
  uint8_t*  S4  = ws + 10649600;                //    819,200 B [10][8][16][20][32] u8
  float*    sb  = (float*)(ws + 11468800);      //    327,680 B [8][10240] f32
  float*    pt  = (float*)(ws + 11796480);      //  1,048,576 B [8][8][4096] f32
  float*    pt2 = (float*)(ws + 12845056);      //        512 B [128] f32

  k_l1 <<<2560, 256, 0, stream>>>(x, w1, b1, S1);
  k_l2 <<<1280, 256, 0, stream>>>(S1, w2, b2, S2);
  k_l3 <<<1280, 256, 0, stream>>>(S2, w3, b3, S3);
  k_l4 <<<1280, 256, 0, stream>>>(S3, w4, b4, S4);
  k_l5 <<< 640, 256, 0, stream>>>(S4, w5, b5, sb);
  k_fc1<<<1024, 256, 0, stream>>>(sb, fc1w, pt);
  k_fc2p<<<128, 64, 0, stream>>>(pt, fc1b, fc2w, pt2);
  k_fc3<<<   1, 64, 0, stream>>>(pt2, fc2b, (float*)d_out);
}